// Round 7
// baseline (92.054 us; speedup 1.0000x reference)
//
#include <hip/hip_runtime.h>
#include <hip/hip_bf16.h>

#define DIM 768
#define EPS 1e-8f

// Kernel A: one block (512 thr = 8 waves) per example, wave-autonomous:
//  - each wave loads the anchor row itself (3 float4/lane; L1/L2-cached)
//  - each wave scans the L2-resident lens arrays itself (int4 loads)
//  - cosines: 2 vectors per wave per round, all 6 float4 HBM loads issued
//    into registers before any FMA/reduce (max memory-level parallelism)
//  - only 2 __syncthreads (publish cosines, block-reduce pair sum)
__global__ __launch_bounds__(512, 8) void triplet_partials(
    const float* __restrict__ anchor, const float* __restrict__ positive,
    const float* __restrict__ negative,
    const int* __restrict__ p_lens, const int* __restrict__ n_lens,
    float* __restrict__ partials, int bs)
{
    const int b = blockIdx.x;
    const int tid = threadIdx.x;
    const int wave = tid >> 6;
    const int lane = tid & 63;

    __shared__ float sCos[32];      // up to 12 pos + 12 neg
    __shared__ float sRedF[8];

    // ---- anchor row into registers (HBM for first wave, cache after) ----
    const float4* a4 = (const float4*)(anchor + (size_t)b * DIM);
    const float4 av0 = a4[lane];
    const float4 av1 = a4[lane + 64];
    const float4 av2 = a4[lane + 128];

    // ---- per-wave scan of lens arrays (int4, L2-resident) ----
    int pre_p = 0, pre_n = 0, tot = 0;
    const int4* p4 = (const int4*)p_lens;
    const int4* n4 = (const int4*)n_lens;
    const int nq = bs >> 2;
    for (int q = lane; q < nq; q += 64) {
        int4 pv = p4[q];
        int4 nv = n4[q];
        int base = q << 2;
        pre_p += (base     < b ? pv.x : 0) + (base + 1 < b ? pv.y : 0)
               + (base + 2 < b ? pv.z : 0) + (base + 3 < b ? pv.w : 0);
        pre_n += (base     < b ? nv.x : 0) + (base + 1 < b ? nv.y : 0)
               + (base + 2 < b ? nv.z : 0) + (base + 3 < b ? nv.w : 0);
        tot += pv.x * nv.x + pv.y * nv.y + pv.z * nv.z + pv.w * nv.w;
    }
    for (int i = (nq << 2) + lane; i < bs; i += 64) {   // tail (bs % 4)
        int p = p_lens[i], n = n_lens[i];
        if (i < b) { pre_p += p; pre_n += n; }
        tot += p * n;
    }

    float asq = av0.x*av0.x + av0.y*av0.y + av0.z*av0.z + av0.w*av0.w
              + av1.x*av1.x + av1.y*av1.y + av1.z*av1.z + av1.w*av1.w
              + av2.x*av2.x + av2.y*av2.y + av2.z*av2.z + av2.w*av2.w;

    #pragma unroll
    for (int s = 32; s > 0; s >>= 1) {   // butterfly: all lanes get totals
        asq   += __shfl_xor(asq, s);
        pre_p += __shfl_xor(pre_p, s);
        pre_n += __shfl_xor(pre_n, s);
        tot   += __shfl_xor(tot, s);
    }
    const float an = sqrtf(asq);
    const int po = pre_p, no = pre_n;

    const int pl = p_lens[b];    // uniform -> scalar load, cache hit
    const int nl = n_lens[b];
    const int nvec = pl + nl;

    // ---- cosines: 2 vectors per wave per round ----
    for (int v0 = wave * 2; v0 < nvec; v0 += 16) {
        const int v1 = v0 + 1;
        const bool has1 = (v1 < nvec);

        const float* x0p = (v0 < pl)
            ? positive + (size_t)(po + v0) * DIM
            : negative + (size_t)(no + (v0 - pl)) * DIM;
        const float4 x0a = ((const float4*)x0p)[lane];
        const float4 x0b = ((const float4*)x0p)[lane + 64];
        const float4 x0c = ((const float4*)x0p)[lane + 128];

        float4 x1a = make_float4(0.f,0.f,0.f,0.f), x1b = x1a, x1c = x1a;
        if (has1) {
            const float* x1p = (v1 < pl)
                ? positive + (size_t)(po + v1) * DIM
                : negative + (size_t)(no + (v1 - pl)) * DIM;
            x1a = ((const float4*)x1p)[lane];
            x1b = ((const float4*)x1p)[lane + 64];
            x1c = ((const float4*)x1p)[lane + 128];
        }

        float d0 = av0.x*x0a.x + av0.y*x0a.y + av0.z*x0a.z + av0.w*x0a.w
                 + av1.x*x0b.x + av1.y*x0b.y + av1.z*x0b.z + av1.w*x0b.w
                 + av2.x*x0c.x + av2.y*x0c.y + av2.z*x0c.z + av2.w*x0c.w;
        float q0 = x0a.x*x0a.x + x0a.y*x0a.y + x0a.z*x0a.z + x0a.w*x0a.w
                 + x0b.x*x0b.x + x0b.y*x0b.y + x0b.z*x0b.z + x0b.w*x0b.w
                 + x0c.x*x0c.x + x0c.y*x0c.y + x0c.z*x0c.z + x0c.w*x0c.w;
        float d1 = av0.x*x1a.x + av0.y*x1a.y + av0.z*x1a.z + av0.w*x1a.w
                 + av1.x*x1b.x + av1.y*x1b.y + av1.z*x1b.z + av1.w*x1b.w
                 + av2.x*x1c.x + av2.y*x1c.y + av2.z*x1c.z + av2.w*x1c.w;
        float q1 = x1a.x*x1a.x + x1a.y*x1a.y + x1a.z*x1a.z + x1a.w*x1a.w
                 + x1b.x*x1b.x + x1b.y*x1b.y + x1b.z*x1b.z + x1b.w*x1b.w
                 + x1c.x*x1c.x + x1c.y*x1c.y + x1c.z*x1c.z + x1c.w*x1c.w;

        #pragma unroll
        for (int s = 32; s > 0; s >>= 1) {
            d0 += __shfl_xor(d0, s);
            q0 += __shfl_xor(q0, s);
            d1 += __shfl_xor(d1, s);
            q1 += __shfl_xor(q1, s);
        }
        if (lane == 0) {
            sCos[v0] = d0 / fmaxf(an * sqrtf(q0), EPS);
            if (has1) sCos[v1] = d1 / fmaxf(an * sqrtf(q1), EPS);
        }
    }
    __syncthreads();

    // ---- pair hinge sum: max(c_an - c_ap + 1, 0) ----
    const int pairs = pl * nl;
    float s = 0.0f;
    for (int t = tid; t < pairs; t += 512) {
        int j = t / nl;
        int k = t - j * nl;
        s += fmaxf(sCos[pl + k] - sCos[j] + 1.0f, 0.0f);
    }
    #pragma unroll
    for (int sh = 32; sh > 0; sh >>= 1) s += __shfl_xor(s, sh);
    if (lane == 0) sRedF[wave] = s;
    __syncthreads();
    if (tid == 0) {
        float blk = 0.0f;
        #pragma unroll
        for (int w = 0; w < 8; ++w) blk += sRedF[w];
        partials[b] = blk / (float)tot;
    }
}

// Kernel B: single block, deterministic float4 reduce of per-example partials.
__global__ __launch_bounds__(256) void reduce_partials(
    const float* __restrict__ partials, float* __restrict__ out, int bs)
{
    const int tid = threadIdx.x;
    const int wave = tid >> 6;
    const int lane = tid & 63;
    __shared__ float sw[4];

    float s = 0.0f;
    const float4* p4 = (const float4*)partials;
    const int nq = bs >> 2;
    for (int q = tid; q < nq; q += 256) {
        float4 v = p4[q];
        s += v.x + v.y + v.z + v.w;
    }
    for (int i = (nq << 2) + tid; i < bs; i += 256) s += partials[i];
    #pragma unroll
    for (int sh = 32; sh > 0; sh >>= 1) s += __shfl_xor(s, sh);
    if (lane == 0) sw[wave] = s;
    __syncthreads();
    if (tid == 0) *out = sw[0] + sw[1] + sw[2] + sw[3];
}

extern "C" void kernel_launch(void* const* d_in, const int* in_sizes, int n_in,
                              void* d_out, int out_size, void* d_ws, size_t ws_size,
                              hipStream_t stream) {
    const float* anchor   = (const float*)d_in[0];
    const float* positive = (const float*)d_in[1];
    const float* negative = (const float*)d_in[2];
    const int*   p_lens   = (const int*)d_in[3];
    const int*   n_lens   = (const int*)d_in[4];
    float* out = (float*)d_out;

    const int bs = in_sizes[3];   // 1024
    float* partials = (float*)d_ws;

    triplet_partials<<<bs, 512, 0, stream>>>(anchor, positive, negative,
                                             p_lens, n_lens, partials, bs);
    reduce_partials<<<1, 256, 0, stream>>>(partials, out, bs);
}